// Round 1
// baseline (548.381 us; speedup 1.0000x reference)
//
#include <hip/hip_runtime.h>
#include <math.h>

// Problem constants. Device dtypes: all 12 inputs fp32, OUTPUT fp32.
#define BB 4
#define SS 4096
#define HH 8
#define DI 128
#define DOo 128
#define HD 1024        // HH*DI
#define NTOK (BB*SS)   // 16384
#define LNEPS 1e-6f

// cumsum chunking
#define CS1 64
#define NC1 64         // SS/CS1
// recurrence chunking
#define CS2 128
#define NC2 32         // SS/CS2

typedef unsigned short ubf;   // bf16 bits
typedef __attribute__((ext_vector_type(8))) short    bf16x8;
typedef __attribute__((ext_vector_type(8))) unsigned short u16x8;
typedef __attribute__((ext_vector_type(4))) unsigned short u16x4;
typedef __attribute__((ext_vector_type(2))) unsigned short u16x2;
typedef __attribute__((ext_vector_type(4))) float    f32x4;

__device__ __forceinline__ float bf2f(ubf x) {
    union { unsigned int u; float f; } v; v.u = ((unsigned int)x) << 16; return v.f;
}
__device__ __forceinline__ ubf f2bf(float f) {
    union { float f; unsigned int u; } v; v.f = f;
    unsigned int r = v.u + 0x7FFFu + ((v.u >> 16) & 1u);   // RNE
    return (ubf)(r >> 16);
}
__device__ __forceinline__ float fast_sigmoid(float x) {
    // native exp (v_exp_f32) + native rcp: ~4 VALU ops, ~1ulp each — far below bf16 noise
    return __builtin_amdgcn_rcpf(1.f + __expf(-x));
}

// ---------------- block-wide reduction of two floats over blockDim.x (multiple of 64, <=1024)
__device__ __forceinline__ void blockReduce2(float& a, float& b, float2* scratch) {
    __syncthreads();
    int lane = threadIdx.x & 63;
    int wid  = threadIdx.x >> 6;
    #pragma unroll
    for (int off = 32; off > 0; off >>= 1) {
        a += __shfl_down(a, off);
        b += __shfl_down(b, off);
    }
    if (lane == 0) scratch[wid] = make_float2(a, b);
    __syncthreads();
    int nw = blockDim.x >> 6;
    if (wid == 0) {
        float2 v = (lane < nw) ? scratch[lane] : make_float2(0.f, 0.f);
        a = v.x; b = v.y;
        #pragma unroll
        for (int off = 8; off > 0; off >>= 1) {
            a += __shfl_down(a, off);
            b += __shfl_down(b, off);
        }
        if (lane == 0) scratch[0] = make_float2(a, b);
    }
    __syncthreads();
    float2 r = scratch[0];
    a = r.x; b = r.y;
}

// ---------------- KWT: W[h][256][NB] fp32 -> Wt[h][NB][256] bf16 (transpose for k-contiguous frags)
__global__ void kwt(const float* __restrict__ W, ubf* __restrict__ Wt, int NB) {
    int b = blockIdx.x;           // h*NB + n
    int h = b / NB, n = b % NB;
    int k = threadIdx.x;          // 0..255
    Wt[((size_t)h * NB + n) * 256 + k] = f2bf(W[((size_t)h * 256 + k) * NB + n]);
}

// ---------------- K1: per-chunk sums along S for the cumsum + emit in as bf16
__global__ void k1_chunksum(const float* __restrict__ in, float* __restrict__ chunk,
                            ubf* __restrict__ in_bf) {
    int bid = blockIdx.x;                 // b*HH*NC1 + h*NC1 + c
    int c = bid % NC1;
    int h = (bid / NC1) % HH;
    int b = bid / (NC1 * HH);
    int d = threadIdx.x;                  // 0..127
    size_t base = (size_t)(b * SS + c * CS1) * HD + h * DI + d;
    float s = 0.f;
    for (int i = 0; i < CS1; ++i) {
        float v = in[base + (size_t)i * HD];
        in_bf[base + (size_t)i * HD] = f2bf(v);
        s += v;
    }
    chunk[((b * NC1 + c) * HH + h) * DI + d] = s;
}

// ---------------- K2: serial exclusive scan over chunks (in-place)
__global__ void k2_chunkscan(float* __restrict__ chunk) {
    int bid = blockIdx.x;                 // b*HH + h
    int h = bid % HH;
    int b = bid / HH;
    int d = threadIdx.x;
    float run = 0.f;
    for (int c = 0; c < NC1; ++c) {
        int idx = ((b * NC1 + c) * HH + h) * DI + d;
        float v = chunk[idx];
        chunk[idx] = run;
        run += v;
    }
}

// ---------------- K3: in-chunk exclusive cumsum + LayerNorm over (H,DI)=1024 per token -> csln bf16
__global__ void __launch_bounds__(1024) k3_csum_ln(
        const float* __restrict__ in, const float* __restrict__ chunkpre,
        const float* __restrict__ g, const float* __restrict__ beta,
        ubf* __restrict__ out) {
    __shared__ float2 scratch[16];
    int c = blockIdx.x % NC1;
    int b = blockIdx.x / NC1;
    int t = threadIdx.x;                  // h*DI + d, 0..1023
    float run = chunkpre[(b * NC1 + c) * HD + t];
    const float* pin = in + (size_t)(b * SS + c * CS1) * HD + t;
    ubf* pout = out + (size_t)(b * SS + c * CS1) * HD + t;
    float gg = g[t], bb = beta[t];
    for (int i = 0; i < CS1; ++i) {
        float v = pin[(size_t)i * HD];
        float cs = run;
        run += v;
        float a = cs, b2 = cs * cs;
        blockReduce2(a, b2, scratch);
        float mu  = a * (1.f / 1024.f);
        float var = b2 * (1.f / 1024.f) - mu * mu;
        float r = rsqrtf(var + LNEPS);
        pout[(size_t)i * HD] = f2bf((cs - mu) * r * gg + bb);
    }
}

// ---------------- GEMM (MFMA): per-head C[tok][h*NB+n] = [Ab0_h | Ab1_h](tok, 256) @ Wt[h]^T
// Ab0/Ab1: [NTOK][1024] bf16, head slice at h*128, each 128 wide (k<128 / k>=128).
// Wt: [H][NB][256] bf16 (n-major, k-contiguous). C: [NTOK][H*NB] bf16 (no bias).
// BM=128, BN=128, BK=32; 256 threads = 4 waves; wave = 64x64 via 4x4 mfma_16x16x32.
__global__ void __launch_bounds__(256) gemm_h(
        const ubf* __restrict__ Ab0, const ubf* __restrict__ Ab1,
        const ubf* __restrict__ Wt, ubf* __restrict__ C, int NB) {
    __shared__ __align__(16) ubf As[128 * 32];   // fragment-packed: ((mt*64 + kq*16 + mr)*8 + kj)
    __shared__ __align__(16) ubf Bs[128 * 32];
    int tok0 = blockIdx.x * 128;
    int h = blockIdx.y;
    int n0 = blockIdx.z * 128;
    int t = threadIdx.x;
    int lane = t & 63, w = t >> 6;
    int crs = NB * HH;                    // C row stride

    f32x4 acc[4][4];
    #pragma unroll
    for (int i = 0; i < 4; ++i)
        #pragma unroll
        for (int j = 0; j < 4; ++j) acc[i][j] = (f32x4){0.f, 0.f, 0.f, 0.f};

    for (int ks = 0; ks < 8; ++ks) {
        int k0 = ks * 32;
        const ubf* Asrc = (k0 < 128) ? Ab0 : Ab1;
        int kk = k0 & 127;
        __syncthreads();
        // stage A: 128 rows x 32 k = 512 x b128
        #pragma unroll
        for (int it = 0; it < 2; ++it) {
            int slot = it * 256 + t;
            int row = slot >> 2, kq = slot & 3;
            u16x8 v = *(const u16x8*)(Asrc + (size_t)(tok0 + row) * HD + h * DI + kk + kq * 8);
            *(u16x8*)(As + ((row >> 4) * 64 + kq * 16 + (row & 15)) * 8) = v;
        }
        // stage B: 128 n-rows x 32 k
        #pragma unroll
        for (int it = 0; it < 2; ++it) {
            int slot = it * 256 + t;
            int nrow = slot >> 2, kq = slot & 3;
            u16x8 v = *(const u16x8*)(Wt + ((size_t)h * NB + n0 + nrow) * 256 + k0 + kq * 8);
            *(u16x8*)(Bs + ((nrow >> 4) * 64 + kq * 16 + (nrow & 15)) * 8) = v;
        }
        __syncthreads();
        int mb = (w & 1) * 4, nb = (w >> 1) * 4;
        bf16x8 af[4], bfr[4];
        #pragma unroll
        for (int i = 0; i < 4; ++i) af[i]  = *(const bf16x8*)(As + ((mb + i) * 64 + lane) * 8);
        #pragma unroll
        for (int i = 0; i < 4; ++i) bfr[i] = *(const bf16x8*)(Bs + ((nb + i) * 64 + lane) * 8);
        #pragma unroll
        for (int i = 0; i < 4; ++i)
            #pragma unroll
            for (int j = 0; j < 4; ++j)
                acc[i][j] = __builtin_amdgcn_mfma_f32_16x16x32_bf16(af[i], bfr[j], acc[i][j], 0, 0, 0);
    }
    // epilogue: C/D layout col=lane&15, row=quad*4+reg  (m89/m91-verified)
    int mbase = tok0 + (w & 1) * 64 + (lane >> 4) * 4;
    int nbase = h * NB + n0 + (w >> 1) * 64 + (lane & 15);
    #pragma unroll
    for (int i = 0; i < 4; ++i)
        #pragma unroll
        for (int j = 0; j < 4; ++j) {
            #pragma unroll
            for (int r = 0; r < 4; ++r)
                C[(size_t)(mbase + i * 16 + r) * crs + nbase + j * 16] = f2bf(acc[i][j][r]);
        }
}

// ---------------- K4b (wave-per-token): +bias, LN over (H,3,DO)=3072 per token, gates.
// One wave owns one token: 48 elems/lane (24 segments x u16x2), butterfly shfl reduce,
// zero barriers. LN params (bias/g/beta, 144 floats/lane) hoisted to regs, amortized
// over 4 tokens/wave. Raw next-token loads ping-pong prefetched (A/B) to hide HBM latency.
// fgl = forget LOGIT bf16 (ws); igh = sigmoid(i)*relu(h) fp32 -> d_out.
#define K4B_PROC(RAW, TOK) do {                                                          \
    float sum = 0.f, sq = 0.f;                                                           \
    _Pragma("unroll")                                                                    \
    for (int s = 0; s < 24; ++s) {                                                       \
        float a_ = bf2f(RAW[s].x) + pb[s].x;                                             \
        float b_ = bf2f(RAW[s].y) + pb[s].y;                                             \
        sum += a_ + b_; sq += a_ * a_ + b_ * b_;                                         \
    }                                                                                    \
    _Pragma("unroll")                                                                    \
    for (int m_ = 32; m_ >= 1; m_ >>= 1) {                                               \
        sum += __shfl_xor(sum, m_); sq += __shfl_xor(sq, m_);                            \
    }                                                                                    \
    float mu = sum * (1.f / 3072.f);                                                     \
    float r  = rsqrtf(sq * (1.f / 3072.f) - mu * mu + LNEPS);                            \
    size_t ob = (size_t)(TOK) * HD + col;                                                \
    _Pragma("unroll")                                                                    \
    for (int h = 0; h < 8; ++h) {                                                        \
        int si = h * 3, sf = si + 1, sh = si + 2;                                        \
        float vix = bf2f(RAW[si].x) + pb[si].x, viy = bf2f(RAW[si].y) + pb[si].y;        \
        float vfx = bf2f(RAW[sf].x) + pb[sf].x, vfy = bf2f(RAW[sf].y) + pb[sf].y;        \
        float vhx = bf2f(RAW[sh].x) + pb[sh].x, vhy = bf2f(RAW[sh].y) + pb[sh].y;        \
        float lix = (vix - mu) * r * pg[si].x + pe[si].x;                                \
        float liy = (viy - mu) * r * pg[si].y + pe[si].y;                                \
        float lfx = (vfx - mu) * r * pg[sf].x + pe[sf].x;                                \
        float lfy = (vfy - mu) * r * pg[sf].y + pe[sf].y;                                \
        float lhx = (vhx - mu) * r * pg[sh].x + pe[sh].x;                                \
        float lhy = (vhy - mu) * r * pg[sh].y + pe[sh].y;                                \
        u16x2 fo; fo.x = f2bf(lfx); fo.y = f2bf(lfy);                                    \
        *(u16x2*)(fgl + ob + h * 128) = fo;                                              \
        float2 io;                                                                       \
        io.x = fast_sigmoid(lix) * fmaxf(lhx, 0.f);                                      \
        io.y = fast_sigmoid(liy) * fmaxf(lhy, 0.f);                                      \
        *(float2*)(igh + ob + h * 128) = io;                                             \
    }                                                                                    \
} while (0)

__global__ void __launch_bounds__(256, 2) k4b_ln_gates(
        const ubf* __restrict__ h3, const float* __restrict__ bias,
        const float* __restrict__ g, const float* __restrict__ beta,
        ubf* __restrict__ fgl, float* __restrict__ igh) {
    int lane = threadIdx.x & 63;
    int wid  = blockIdx.x * 4 + (threadIdx.x >> 6);   // global wave id, 0..4095
    int tok0 = wid * 4;                               // 4 consecutive tokens per wave
    int col  = 2 * lane;

    // LN params: 24 segments (h*3+p) x 2 columns -> registers, reused across 4 tokens
    float2 pb[24], pg[24], pe[24];
    #pragma unroll
    for (int s = 0; s < 24; ++s) {
        pb[s] = *(const float2*)(bias + s * 128 + col);
        pg[s] = *(const float2*)(g    + s * 128 + col);
        pe[s] = *(const float2*)(beta + s * 128 + col);
    }

    const ubf* ptok = h3 + (size_t)tok0 * 3072 + col;
    u16x2 rawA[24], rawB[24];
    #pragma unroll
    for (int s = 0; s < 24; ++s) rawA[s] = *(const u16x2*)(ptok + s * 128);
    #pragma unroll
    for (int s = 0; s < 24; ++s) rawB[s] = *(const u16x2*)(ptok + 3072 + s * 128);
    K4B_PROC(rawA, tok0 + 0);
    #pragma unroll
    for (int s = 0; s < 24; ++s) rawA[s] = *(const u16x2*)(ptok + 2 * 3072 + s * 128);
    K4B_PROC(rawB, tok0 + 1);
    #pragma unroll
    for (int s = 0; s < 24; ++s) rawB[s] = *(const u16x2*)(ptok + 3 * 3072 + s * 128);
    K4B_PROC(rawA, tok0 + 2);
    K4B_PROC(rawB, tok0 + 3);
}

// ---------------- K5a: per-chunk recurrence summary: P = prod f, L = local end value
__global__ void k5a_chunkrec(const ubf* __restrict__ fgl, const float* __restrict__ igh,
                             float* __restrict__ Pb, float* __restrict__ Lb) {
    int bid = blockIdx.x;                 // b*NC2*HH + c*HH + h
    int h = bid % HH;
    int c = (bid / HH) % NC2;
    int b = bid / (HH * NC2);
    int d = threadIdx.x;
    size_t base = (size_t)(b * SS + c * CS2) * HD + h * DOo + d;
    float P = 1.f, L = 0.f;
    for (int s = 0; s < CS2; ++s) {
        float f = 1.f / (1.f + expf(-bf2f(fgl[base + (size_t)s * HD])));
        float i = igh[base + (size_t)s * HD];
        L = f * L + i;
        P *= f;
    }
    int o = ((b * NC2 + c) * HH + h) * DOo + d;
    Pb[o] = P;
    Lb[o] = L;
}

// ---------------- K5b: serial carry across chunks
__global__ void k5b_carry(const float* __restrict__ Pb, const float* __restrict__ Lb,
                          const float* __restrict__ init_cx, float* __restrict__ cIn) {
    int bid = blockIdx.x;                 // b*HH + h
    int h = bid % HH;
    int b = bid / HH;
    int d = threadIdx.x;
    float c = init_cx[h * DOo + d];
    for (int cc = 0; cc < NC2; ++cc) {
        int o = ((b * NC2 + cc) * HH + h) * DOo + d;
        cIn[o] = c;
        c = Pb[o] * c + Lb[o];
    }
}

// ---------------- K5c: final in-chunk recurrence; cell fp32 in-place over igh (d_out) + cell bf16 copy
__global__ void k5c_cell(const ubf* __restrict__ fgl, float* __restrict__ igh_cell,
                         const float* __restrict__ cIn, ubf* __restrict__ cell_bf) {
    int bid = blockIdx.x;
    int h = bid % HH;
    int c = (bid / HH) % NC2;
    int b = bid / (HH * NC2);
    int d = threadIdx.x;
    size_t base = (size_t)(b * SS + c * CS2) * HD + h * DOo + d;
    int o = ((b * NC2 + c) * HH + h) * DOo + d;
    float cv = cIn[o];
    for (int s = 0; s < CS2; ++s) {
        float f = 1.f / (1.f + expf(-bf2f(fgl[base + (size_t)s * HD])));
        float i = igh_cell[base + (size_t)s * HD];
        cv = f * cv + i;
        igh_cell[base + (size_t)s * HD] = cv;
        cell_bf[base + (size_t)s * HD] = f2bf(cv);
    }
}

// ---------------- K6b (wave-per-token): +bias, LN over 1024 per token, sigmoid*cell -> out (in place).
// 16 elems/lane (8 segments x u16x2). All 4 tokens' og+cell loads issued up-front
// (pure-register compute after), params in regs across tokens, zero barriers.
__global__ void __launch_bounds__(256) k6b_ln_out(
        const ubf* __restrict__ ogr, float* __restrict__ out /* cell in, final out */,
        const float* __restrict__ bias, const float* __restrict__ g,
        const float* __restrict__ beta) {
    int lane = threadIdx.x & 63;
    int wid  = blockIdx.x * 4 + (threadIdx.x >> 6);   // 0..4095
    int tok0 = wid * 4;
    int col  = 2 * lane;

    float2 pb[8], pg[8], pe[8];
    #pragma unroll
    for (int s = 0; s < 8; ++s) {
        pb[s] = *(const float2*)(bias + s * 128 + col);
        pg[s] = *(const float2*)(g    + s * 128 + col);
        pe[s] = *(const float2*)(beta + s * 128 + col);
    }

    u16x2  og[4][8];
    float2 cl[4][8];
    #pragma unroll
    for (int t = 0; t < 4; ++t) {
        size_t base = (size_t)(tok0 + t) * HD + col;
        #pragma unroll
        for (int s = 0; s < 8; ++s) {
            og[t][s] = *(const u16x2*)(ogr + base + s * 128);
            cl[t][s] = *(const float2*)(out + base + s * 128);
        }
    }

    #pragma unroll
    for (int t = 0; t < 4; ++t) {
        float sum = 0.f, sq = 0.f;
        #pragma unroll
        for (int s = 0; s < 8; ++s) {
            float a = bf2f(og[t][s].x) + pb[s].x;
            float b = bf2f(og[t][s].y) + pb[s].y;
            sum += a + b; sq += a * a + b * b;
        }
        #pragma unroll
        for (int m = 32; m >= 1; m >>= 1) {
            sum += __shfl_xor(sum, m); sq += __shfl_xor(sq, m);
        }
        float mu = sum * (1.f / 1024.f);
        float r  = rsqrtf(sq * (1.f / 1024.f) - mu * mu + LNEPS);
        size_t base = (size_t)(tok0 + t) * HD + col;
        #pragma unroll
        for (int s = 0; s < 8; ++s) {
            float a = bf2f(og[t][s].x) + pb[s].x;
            float b = bf2f(og[t][s].y) + pb[s].y;
            float la = (a - mu) * r * pg[s].x + pe[s].x;
            float lb = (b - mu) * r * pg[s].y + pe[s].y;
            float2 o;
            o.x = fast_sigmoid(la) * cl[t][s].x;
            o.y = fast_sigmoid(lb) * cl[t][s].y;
            *(float2*)(out + base + s * 128) = o;
        }
    }
}

extern "C" void kernel_launch(void* const* d_in, const int* in_sizes, int n_in,
                              void* d_out, int out_size, void* d_ws, size_t ws_size,
                              hipStream_t stream) {
    const float* heads_input = (const float*)d_in[0];
    const float* W_hid   = (const float*)d_in[1];
    const float* b_hid   = (const float*)d_in[2];
    const float* g_csum  = (const float*)d_in[3];
    const float* beta_csum = (const float*)d_in[4];
    const float* g_hid   = (const float*)d_in[5];
    const float* beta_hid = (const float*)d_in[6];
    const float* W_og    = (const float*)d_in[7];
    const float* b_og    = (const float*)d_in[8];
    const float* g_og    = (const float*)d_in[9];
    const float* beta_og = (const float*)d_in[10];
    const float* init_cx = (const float*)d_in[11];
    float* out = (float*)d_out;           // fp32 output, NTOK*HD elements

    // workspace layout (~172.5 MB)
    char* ws = (char*)d_ws;
    ubf* in_bf   = (ubf*)ws;                                   // 33,554,432 B
    ubf* csln_bf = (ubf*)(ws + (size_t)33554432);              // 33,554,432 B (later fgl)
    ubf* big     = (ubf*)(ws + (size_t)67108864);              // 100,663,296 B
    ubf* h3      = big;                                        // k4a w, k4b r
    ubf* cell_bf = big;                                        // k5c w, k6a r (h3 dead)
    ubf* og_bf   = big + (size_t)NTOK * HD;                    // k6a w, k6b r
    char* tail   = ws + (size_t)167772160;
    float* chunk = (float*)tail;                               // 1,048,576 B
    float* Pb    = chunk + (size_t)BB * NC1 * HD;              //   524,288 B
    float* Lb    = Pb + (size_t)BB * NC2 * HD;                 //   524,288 B
    float* cIn   = Lb + (size_t)BB * NC2 * HD;                 //   524,288 B
    ubf* Wt_hid  = (ubf*)(cIn + (size_t)BB * NC2 * HD);        // 1,572,864 B
    ubf* Wt_og   = Wt_hid + (size_t)HH * 384 * 256;            //   524,288 B
    ubf* fgl     = csln_bf;   // alias: csln consumed by gemm(k4a) before k4b writes fgl

    kwt<<<HH * 384, 256, 0, stream>>>(W_hid, Wt_hid, 384);
    kwt<<<HH * 128, 256, 0, stream>>>(W_og, Wt_og, 128);
    k1_chunksum<<<BB * HH * NC1, 128, 0, stream>>>(heads_input, chunk, in_bf);
    k2_chunkscan<<<BB * HH, 128, 0, stream>>>(chunk);
    k3_csum_ln<<<BB * NC1, 1024, 0, stream>>>(heads_input, chunk, g_csum, beta_csum, csln_bf);
    gemm_h<<<dim3(NTOK / 128, HH, 3), 256, 0, stream>>>(in_bf, csln_bf, Wt_hid, h3, 384);
    k4b_ln_gates<<<NTOK / 16, 256, 0, stream>>>(h3, b_hid, g_hid, beta_hid, fgl, out);
    k5a_chunkrec<<<BB * NC2 * HH, 128, 0, stream>>>(fgl, out, Pb, Lb);
    k5b_carry<<<BB * HH, 128, 0, stream>>>(Pb, Lb, init_cx, cIn);
    k5c_cell<<<BB * NC2 * HH, 128, 0, stream>>>(fgl, out, cIn, cell_bf);
    gemm_h<<<dim3(NTOK / 128, HH, 1), 256, 0, stream>>>(in_bf, cell_bf, Wt_og, og_bf, 128);
    k6b_ln_out<<<NTOK / 16, 256, 0, stream>>>(og_bf, out, b_og, g_og, beta_og);
}

// Round 2
// 485.244 us; speedup vs baseline: 1.1301x; 1.1301x over previous
//
#include <hip/hip_runtime.h>
#include <math.h>

// Problem constants. Device dtypes: all 12 inputs fp32, OUTPUT fp32.
#define BB 4
#define SS 4096
#define HH 8
#define DI 128
#define DOo 128
#define HD 1024        // HH*DI
#define NTOK (BB*SS)   // 16384
#define LNEPS 1e-6f

// cumsum chunking
#define CS1 64
#define NC1 64         // SS/CS1
// recurrence chunking
#define CS2 128
#define NC2 32         // SS/CS2

typedef unsigned short ubf;   // bf16 bits
typedef __attribute__((ext_vector_type(8))) short    bf16x8;
typedef __attribute__((ext_vector_type(8))) unsigned short u16x8;
typedef __attribute__((ext_vector_type(4))) unsigned short u16x4;
typedef __attribute__((ext_vector_type(4))) float    f32x4;

__device__ __forceinline__ float bf2f(ubf x) {
    union { unsigned int u; float f; } v; v.u = ((unsigned int)x) << 16; return v.f;
}
__device__ __forceinline__ ubf f2bf(float f) {
    union { float f; unsigned int u; } v; v.f = f;
    unsigned int r = v.u + 0x7FFFu + ((v.u >> 16) & 1u);   // RNE
    return (ubf)(r >> 16);
}
__device__ __forceinline__ float fast_sigmoid(float x) {
    // native exp (v_exp_f32) + native rcp: ~4 VALU ops, ~1ulp each — far below bf16 noise
    return __builtin_amdgcn_rcpf(1.f + __expf(-x));
}

// ---------------- block-wide reduction of two floats over blockDim.x (multiple of 64, <=1024)
__device__ __forceinline__ void blockReduce2(float& a, float& b, float2* scratch) {
    __syncthreads();
    int lane = threadIdx.x & 63;
    int wid  = threadIdx.x >> 6;
    #pragma unroll
    for (int off = 32; off > 0; off >>= 1) {
        a += __shfl_down(a, off);
        b += __shfl_down(b, off);
    }
    if (lane == 0) scratch[wid] = make_float2(a, b);
    __syncthreads();
    int nw = blockDim.x >> 6;
    if (wid == 0) {
        float2 v = (lane < nw) ? scratch[lane] : make_float2(0.f, 0.f);
        a = v.x; b = v.y;
        #pragma unroll
        for (int off = 8; off > 0; off >>= 1) {
            a += __shfl_down(a, off);
            b += __shfl_down(b, off);
        }
        if (lane == 0) scratch[0] = make_float2(a, b);
    }
    __syncthreads();
    float2 r = scratch[0];
    a = r.x; b = r.y;
}

// ---------------- KWT: W[h][256][NB] fp32 -> Wt[h][NB][256] bf16 (transpose for k-contiguous frags)
__global__ void kwt(const float* __restrict__ W, ubf* __restrict__ Wt, int NB) {
    int b = blockIdx.x;           // h*NB + n
    int h = b / NB, n = b % NB;
    int k = threadIdx.x;          // 0..255
    Wt[((size_t)h * NB + n) * 256 + k] = f2bf(W[((size_t)h * 256 + k) * NB + n]);
}

// ---------------- K1: per-chunk sums along S for the cumsum + emit in as bf16
__global__ void k1_chunksum(const float* __restrict__ in, float* __restrict__ chunk,
                            ubf* __restrict__ in_bf) {
    int bid = blockIdx.x;                 // b*HH*NC1 + h*NC1 + c
    int c = bid % NC1;
    int h = (bid / NC1) % HH;
    int b = bid / (NC1 * HH);
    int d = threadIdx.x;                  // 0..127
    size_t base = (size_t)(b * SS + c * CS1) * HD + h * DI + d;
    float s = 0.f;
    for (int i = 0; i < CS1; ++i) {
        float v = in[base + (size_t)i * HD];
        in_bf[base + (size_t)i * HD] = f2bf(v);
        s += v;
    }
    chunk[((b * NC1 + c) * HH + h) * DI + d] = s;
}

// ---------------- K2: serial exclusive scan over chunks (in-place)
__global__ void k2_chunkscan(float* __restrict__ chunk) {
    int bid = blockIdx.x;                 // b*HH + h
    int h = bid % HH;
    int b = bid / HH;
    int d = threadIdx.x;
    float run = 0.f;
    for (int c = 0; c < NC1; ++c) {
        int idx = ((b * NC1 + c) * HH + h) * DI + d;
        float v = chunk[idx];
        chunk[idx] = run;
        run += v;
    }
}

// ---------------- K3: in-chunk exclusive cumsum + LayerNorm over (H,DI)=1024 per token -> csln bf16
__global__ void __launch_bounds__(1024) k3_csum_ln(
        const float* __restrict__ in, const float* __restrict__ chunkpre,
        const float* __restrict__ g, const float* __restrict__ beta,
        ubf* __restrict__ out) {
    __shared__ float2 scratch[16];
    int c = blockIdx.x % NC1;
    int b = blockIdx.x / NC1;
    int t = threadIdx.x;                  // h*DI + d, 0..1023
    float run = chunkpre[(b * NC1 + c) * HD + t];
    const float* pin = in + (size_t)(b * SS + c * CS1) * HD + t;
    ubf* pout = out + (size_t)(b * SS + c * CS1) * HD + t;
    float gg = g[t], bb = beta[t];
    for (int i = 0; i < CS1; ++i) {
        float v = pin[(size_t)i * HD];
        float cs = run;
        run += v;
        float a = cs, b2 = cs * cs;
        blockReduce2(a, b2, scratch);
        float mu  = a * (1.f / 1024.f);
        float var = b2 * (1.f / 1024.f) - mu * mu;
        float r = rsqrtf(var + LNEPS);
        pout[(size_t)i * HD] = f2bf((cs - mu) * r * gg + bb);
    }
}

// ---------------- GEMM (MFMA): per-head C over [Ab0_h | Ab1_h](tok, 256) @ Wt[h]^T, +bias (fp32, pre-round)
// Ab0/Ab1: [NTOK][1024] bf16, head slice at h*128, each 128 wide (k<128 / k>=128).
// Wt: [H][NB][256] bf16 (n-major, k-contiguous). bias: [H][NB] fp32.
// C layout PERMUTED for lane-local gates: col = (n>>7)*1024 + h*128 + (n&127), row stride NB*8.
//   hid (NB=384): [tok][part][h*128+d]  (3 part-planes of 1024)
//   og  (NB=128): [tok][h*128+d]        (identical to old layout)
// BM=128, BN=128, BK=32; 256 threads = 4 waves; wave = 64x64 via 4x4 mfma_16x16x32.
__global__ void __launch_bounds__(256) gemm_h(
        const ubf* __restrict__ Ab0, const ubf* __restrict__ Ab1,
        const ubf* __restrict__ Wt, const float* __restrict__ bias,
        ubf* __restrict__ C, int NB) {
    __shared__ __align__(16) ubf As[128 * 32];   // fragment-packed: ((mt*64 + kq*16 + mr)*8 + kj)
    __shared__ __align__(16) ubf Bs[128 * 32];
    int tok0 = blockIdx.x * 128;
    int h = blockIdx.y;
    int n0 = blockIdx.z * 128;
    int t = threadIdx.x;
    int lane = t & 63, w = t >> 6;
    int crs = NB * HH;                    // C row stride

    f32x4 acc[4][4];
    #pragma unroll
    for (int i = 0; i < 4; ++i)
        #pragma unroll
        for (int j = 0; j < 4; ++j) acc[i][j] = (f32x4){0.f, 0.f, 0.f, 0.f};

    for (int ks = 0; ks < 8; ++ks) {
        int k0 = ks * 32;
        const ubf* Asrc = (k0 < 128) ? Ab0 : Ab1;
        int kk = k0 & 127;
        __syncthreads();
        // stage A: 128 rows x 32 k = 512 x b128
        #pragma unroll
        for (int it = 0; it < 2; ++it) {
            int slot = it * 256 + t;
            int row = slot >> 2, kq = slot & 3;
            u16x8 v = *(const u16x8*)(Asrc + (size_t)(tok0 + row) * HD + h * DI + kk + kq * 8);
            *(u16x8*)(As + ((row >> 4) * 64 + kq * 16 + (row & 15)) * 8) = v;
        }
        // stage B: 128 n-rows x 32 k
        #pragma unroll
        for (int it = 0; it < 2; ++it) {
            int slot = it * 256 + t;
            int nrow = slot >> 2, kq = slot & 3;
            u16x8 v = *(const u16x8*)(Wt + ((size_t)h * NB + n0 + nrow) * 256 + k0 + kq * 8);
            *(u16x8*)(Bs + ((nrow >> 4) * 64 + kq * 16 + (nrow & 15)) * 8) = v;
        }
        __syncthreads();
        int mb = (w & 1) * 4, nb = (w >> 1) * 4;
        bf16x8 af[4], bfr[4];
        #pragma unroll
        for (int i = 0; i < 4; ++i) af[i]  = *(const bf16x8*)(As + ((mb + i) * 64 + lane) * 8);
        #pragma unroll
        for (int i = 0; i < 4; ++i) bfr[i] = *(const bf16x8*)(Bs + ((nb + i) * 64 + lane) * 8);
        #pragma unroll
        for (int i = 0; i < 4; ++i)
            #pragma unroll
            for (int j = 0; j < 4; ++j)
                acc[i][j] = __builtin_amdgcn_mfma_f32_16x16x32_bf16(af[i], bfr[j], acc[i][j], 0, 0, 0);
    }
    // epilogue: C/D layout col=lane&15, row=quad*4+reg  (m89/m91-verified); +bias, permuted col
    int mbase = tok0 + (w & 1) * 64 + (lane >> 4) * 4;
    int nn = n0 + (w >> 1) * 64 + (lane & 15);
    #pragma unroll
    for (int j = 0; j < 4; ++j) {
        int n = nn + j * 16;
        float bv = bias[h * NB + n];
        int col = (n >> 7) * 1024 + h * 128 + (n & 127);
        #pragma unroll
        for (int i = 0; i < 4; ++i) {
            #pragma unroll
            for (int r = 0; r < 4; ++r)
                C[(size_t)(mbase + i * 16 + r) * crs + col] = f2bf(acc[i][j][r] + bv);
        }
    }
}

// ---------------- K4b (wave-per-token, 16384 waves): LN over 3072 (bias pre-folded in gemm), gates.
// h3' layout [tok][part][h*128+d]: lane owns 8 consecutive cols in each of 3 part-planes x 2 halves
// -> 6 x u16x8 (16B) loads, all gate combos lane-local, zero barriers, butterfly reduce.
// g/beta (36KB, L2-resident) reloaded per token as float4 -> VGPR stays low, occupancy high.
__global__ void __launch_bounds__(256, 4) k4b_ln_gates(
        const ubf* __restrict__ h3, const float* __restrict__ g,
        const float* __restrict__ beta, ubf* __restrict__ fgl, float* __restrict__ igh) {
    int lane = threadIdx.x & 63;
    int tok  = blockIdx.x * 4 + (threadIdx.x >> 6);
    int c0 = 8 * lane;                    // col base within a part-plane (q=1 adds 512)
    const ubf* p = h3 + (size_t)tok * 3072;

    u16x8 raw[6];
    #pragma unroll
    for (int pp = 0; pp < 3; ++pp) {
        raw[pp * 2 + 0] = *(const u16x8*)(p + pp * 1024 + c0);
        raw[pp * 2 + 1] = *(const u16x8*)(p + pp * 1024 + 512 + c0);
    }
    float sum = 0.f, sq = 0.f;
    #pragma unroll
    for (int s = 0; s < 6; ++s) {
        #pragma unroll
        for (int j = 0; j < 8; ++j) {
            float a = bf2f((ubf)raw[s][j]);
            sum += a; sq = fmaf(a, a, sq);
        }
    }
    #pragma unroll
    for (int m = 32; m >= 1; m >>= 1) {
        sum += __shfl_xor(sum, m);
        sq  += __shfl_xor(sq, m);
    }
    float mu = sum * (1.f / 3072.f);
    float r  = rsqrtf(sq * (1.f / 3072.f) - mu * mu + LNEPS);

    int dd = c0 & 127;
    size_t ob = (size_t)tok * HD + c0;
    #pragma unroll
    for (int q = 0; q < 2; ++q) {
        int hq = (c0 + q * 512) >> 7;
        int gb = hq * 384 + dd;           // g_hid/beta_hid are [h][part][d]
        f32x4 gv[3][2], bv[3][2];
        #pragma unroll
        for (int pp = 0; pp < 3; ++pp) {
            gv[pp][0] = *(const f32x4*)(g + gb + pp * 128);
            gv[pp][1] = *(const f32x4*)(g + gb + pp * 128 + 4);
            bv[pp][0] = *(const f32x4*)(beta + gb + pp * 128);
            bv[pp][1] = *(const f32x4*)(beta + gb + pp * 128 + 4);
        }
        u16x8 fo;
        f32x4 io0, io1;
        #pragma unroll
        for (int j = 0; j < 8; ++j) {
            float ai = bf2f((ubf)raw[0 + q][j]);
            float af = bf2f((ubf)raw[2 + q][j]);
            float ah = bf2f((ubf)raw[4 + q][j]);
            float li = (ai - mu) * r * gv[0][j >> 2][j & 3] + bv[0][j >> 2][j & 3];
            float lf = (af - mu) * r * gv[1][j >> 2][j & 3] + bv[1][j >> 2][j & 3];
            float lh = (ah - mu) * r * gv[2][j >> 2][j & 3] + bv[2][j >> 2][j & 3];
            fo[j] = f2bf(lf);
            float v = fast_sigmoid(li) * fmaxf(lh, 0.f);
            if (j < 4) io0[j & 3] = v; else io1[j & 3] = v;
        }
        *(u16x8*)(fgl + ob + q * 512) = fo;
        *(f32x4*)(igh + ob + q * 512) = io0;
        *(f32x4*)(igh + ob + q * 512 + 4) = io1;
    }
}

// ---------------- K5a: per-chunk recurrence summary: P = prod f, L = local end value
__global__ void k5a_chunkrec(const ubf* __restrict__ fgl, const float* __restrict__ igh,
                             float* __restrict__ Pb, float* __restrict__ Lb) {
    int bid = blockIdx.x;                 // b*NC2*HH + c*HH + h
    int h = bid % HH;
    int c = (bid / HH) % NC2;
    int b = bid / (HH * NC2);
    int d = threadIdx.x;
    size_t base = (size_t)(b * SS + c * CS2) * HD + h * DOo + d;
    float P = 1.f, L = 0.f;
    for (int s = 0; s < CS2; ++s) {
        float f = 1.f / (1.f + expf(-bf2f(fgl[base + (size_t)s * HD])));
        float i = igh[base + (size_t)s * HD];
        L = f * L + i;
        P *= f;
    }
    int o = ((b * NC2 + c) * HH + h) * DOo + d;
    Pb[o] = P;
    Lb[o] = L;
}

// ---------------- K5b: serial carry across chunks
__global__ void k5b_carry(const float* __restrict__ Pb, const float* __restrict__ Lb,
                          const float* __restrict__ init_cx, float* __restrict__ cIn) {
    int bid = blockIdx.x;                 // b*HH + h
    int h = bid % HH;
    int b = bid / HH;
    int d = threadIdx.x;
    float c = init_cx[h * DOo + d];
    for (int cc = 0; cc < NC2; ++cc) {
        int o = ((b * NC2 + cc) * HH + h) * DOo + d;
        cIn[o] = c;
        c = Pb[o] * c + Lb[o];
    }
}

// ---------------- K5c: final in-chunk recurrence; cell fp32 in-place over igh (d_out) + cell bf16 copy
__global__ void k5c_cell(const ubf* __restrict__ fgl, float* __restrict__ igh_cell,
                         const float* __restrict__ cIn, ubf* __restrict__ cell_bf) {
    int bid = blockIdx.x;
    int h = bid % HH;
    int c = (bid / HH) % NC2;
    int b = bid / (HH * NC2);
    int d = threadIdx.x;
    size_t base = (size_t)(b * SS + c * CS2) * HD + h * DOo + d;
    int o = ((b * NC2 + c) * HH + h) * DOo + d;
    float cv = cIn[o];
    for (int s = 0; s < CS2; ++s) {
        float f = 1.f / (1.f + expf(-bf2f(fgl[base + (size_t)s * HD])));
        float i = igh_cell[base + (size_t)s * HD];
        cv = f * cv + i;
        igh_cell[base + (size_t)s * HD] = cv;
        cell_bf[base + (size_t)s * HD] = f2bf(cv);
    }
}

// ---------------- K6b (wave-per-token): LN over 1024 (bias pre-folded in og gemm), sigmoid*cell -> out.
// 16 elems/lane via 2 x u16x8; cell 4 x float4; params direct-indexed [c] (L2-resident); zero barriers.
__global__ void __launch_bounds__(256, 4) k6b_ln_out(
        const ubf* __restrict__ ogr, float* __restrict__ out /* cell in, final out */,
        const float* __restrict__ g, const float* __restrict__ beta) {
    int lane = threadIdx.x & 63;
    int tok  = blockIdx.x * 4 + (threadIdx.x >> 6);
    int c0 = 8 * lane;
    size_t base = (size_t)tok * HD + c0;

    u16x8 og0 = *(const u16x8*)(ogr + base);
    u16x8 og1 = *(const u16x8*)(ogr + base + 512);
    f32x4 cl[2][2];
    cl[0][0] = *(const f32x4*)(out + base);
    cl[0][1] = *(const f32x4*)(out + base + 4);
    cl[1][0] = *(const f32x4*)(out + base + 512);
    cl[1][1] = *(const f32x4*)(out + base + 512 + 4);

    float sum = 0.f, sq = 0.f;
    #pragma unroll
    for (int j = 0; j < 8; ++j) {
        float a0 = bf2f((ubf)og0[j]);
        float a1 = bf2f((ubf)og1[j]);
        sum += a0 + a1;
        sq = fmaf(a0, a0, sq);
        sq = fmaf(a1, a1, sq);
    }
    #pragma unroll
    for (int m = 32; m >= 1; m >>= 1) {
        sum += __shfl_xor(sum, m);
        sq  += __shfl_xor(sq, m);
    }
    float mu = sum * (1.f / 1024.f);
    float r  = rsqrtf(sq * (1.f / 1024.f) - mu * mu + LNEPS);

    #pragma unroll
    for (int q = 0; q < 2; ++q) {
        f32x4 gv0 = *(const f32x4*)(g + q * 512 + c0);
        f32x4 gv1 = *(const f32x4*)(g + q * 512 + c0 + 4);
        f32x4 bv0 = *(const f32x4*)(beta + q * 512 + c0);
        f32x4 bv1 = *(const f32x4*)(beta + q * 512 + c0 + 4);
        f32x4 o0, o1;
        #pragma unroll
        for (int j = 0; j < 8; ++j) {
            float a = bf2f((ubf)(q ? og1[j] : og0[j]));
            float gg = (j < 4) ? gv0[j & 3] : gv1[j & 3];
            float bb = (j < 4) ? bv0[j & 3] : bv1[j & 3];
            float lo = (a - mu) * r * gg + bb;
            float v = fast_sigmoid(lo) * cl[q][j >> 2][j & 3];
            if (j < 4) o0[j & 3] = v; else o1[j & 3] = v;
        }
        *(f32x4*)(out + base + q * 512) = o0;
        *(f32x4*)(out + base + q * 512 + 4) = o1;
    }
}

extern "C" void kernel_launch(void* const* d_in, const int* in_sizes, int n_in,
                              void* d_out, int out_size, void* d_ws, size_t ws_size,
                              hipStream_t stream) {
    const float* heads_input = (const float*)d_in[0];
    const float* W_hid   = (const float*)d_in[1];
    const float* b_hid   = (const float*)d_in[2];
    const float* g_csum  = (const float*)d_in[3];
    const float* beta_csum = (const float*)d_in[4];
    const float* g_hid   = (const float*)d_in[5];
    const float* beta_hid = (const float*)d_in[6];
    const float* W_og    = (const float*)d_in[7];
    const float* b_og    = (const float*)d_in[8];
    const float* g_og    = (const float*)d_in[9];
    const float* beta_og = (const float*)d_in[10];
    const float* init_cx = (const float*)d_in[11];
    float* out = (float*)d_out;           // fp32 output, NTOK*HD elements

    // workspace layout (~172.5 MB)
    char* ws = (char*)d_ws;
    ubf* in_bf   = (ubf*)ws;                                   // 33,554,432 B
    ubf* csln_bf = (ubf*)(ws + (size_t)33554432);              // 33,554,432 B (later fgl)
    ubf* big     = (ubf*)(ws + (size_t)67108864);              // 100,663,296 B
    ubf* h3      = big;                                        // k4a w, k4b r
    ubf* cell_bf = big;                                        // k5c w, k6a r (h3 dead)
    ubf* og_bf   = big + (size_t)NTOK * HD;                    // k6a w, k6b r
    char* tail   = ws + (size_t)167772160;
    float* chunk = (float*)tail;                               // 1,048,576 B
    float* Pb    = chunk + (size_t)BB * NC1 * HD;              //   524,288 B
    float* Lb    = Pb + (size_t)BB * NC2 * HD;                 //   524,288 B
    float* cIn   = Lb + (size_t)BB * NC2 * HD;                 //   524,288 B
    ubf* Wt_hid  = (ubf*)(cIn + (size_t)BB * NC2 * HD);        // 1,572,864 B
    ubf* Wt_og   = Wt_hid + (size_t)HH * 384 * 256;            //   524,288 B
    ubf* fgl     = csln_bf;   // alias: csln consumed by gemm(k4a) before k4b writes fgl

    kwt<<<HH * 384, 256, 0, stream>>>(W_hid, Wt_hid, 384);
    kwt<<<HH * 128, 256, 0, stream>>>(W_og, Wt_og, 128);
    k1_chunksum<<<BB * HH * NC1, 128, 0, stream>>>(heads_input, chunk, in_bf);
    k2_chunkscan<<<BB * HH, 128, 0, stream>>>(chunk);
    k3_csum_ln<<<BB * NC1, 1024, 0, stream>>>(heads_input, chunk, g_csum, beta_csum, csln_bf);
    gemm_h<<<dim3(NTOK / 128, HH, 3), 256, 0, stream>>>(in_bf, csln_bf, Wt_hid, b_hid, h3, 384);
    k4b_ln_gates<<<NTOK / 4, 256, 0, stream>>>(h3, g_hid, beta_hid, fgl, out);
    k5a_chunkrec<<<BB * NC2 * HH, 128, 0, stream>>>(fgl, out, Pb, Lb);
    k5b_carry<<<BB * HH, 128, 0, stream>>>(Pb, Lb, init_cx, cIn);
    k5c_cell<<<BB * NC2 * HH, 128, 0, stream>>>(fgl, out, cIn, cell_bf);
    gemm_h<<<dim3(NTOK / 128, HH, 1), 256, 0, stream>>>(in_bf, cell_bf, Wt_og, b_og, og_bf, 128);
    k6b_ln_out<<<NTOK / 4, 256, 0, stream>>>(og_bf, out, g_og, beta_og);
}

// Round 3
// 485.132 us; speedup vs baseline: 1.1304x; 1.0002x over previous
//
#include <hip/hip_runtime.h>
#include <math.h>

// Problem constants. Device dtypes: all 12 inputs fp32, OUTPUT fp32.
#define BB 4
#define SS 4096
#define HH 8
#define DI 128
#define DOo 128
#define HD 1024        // HH*DI
#define NTOK (BB*SS)   // 16384
#define LNEPS 1e-6f

// cumsum chunking
#define CS1 64
#define NC1 64         // SS/CS1
// recurrence chunking
#define CS2 128
#define NC2 32         // SS/CS2

typedef unsigned short ubf;   // bf16 bits
typedef __attribute__((ext_vector_type(8))) short    bf16x8;
typedef __attribute__((ext_vector_type(8))) unsigned short u16x8;
typedef __attribute__((ext_vector_type(4))) unsigned short u16x4;
typedef __attribute__((ext_vector_type(4))) float    f32x4;

__device__ __forceinline__ float bf2f(ubf x) {
    union { unsigned int u; float f; } v; v.u = ((unsigned int)x) << 16; return v.f;
}
__device__ __forceinline__ ubf f2bf(float f) {
    union { float f; unsigned int u; } v; v.f = f;
    unsigned int r = v.u + 0x7FFFu + ((v.u >> 16) & 1u);   // RNE
    return (ubf)(r >> 16);
}
__device__ __forceinline__ float fast_sigmoid(float x) {
    return __builtin_amdgcn_rcpf(1.f + __expf(-x));
}

// ---------------- block-wide reduction of two floats over blockDim.x (multiple of 64, <=1024)
__device__ __forceinline__ void blockReduce2(float& a, float& b, float2* scratch) {
    __syncthreads();
    int lane = threadIdx.x & 63;
    int wid  = threadIdx.x >> 6;
    #pragma unroll
    for (int off = 32; off > 0; off >>= 1) {
        a += __shfl_down(a, off);
        b += __shfl_down(b, off);
    }
    if (lane == 0) scratch[wid] = make_float2(a, b);
    __syncthreads();
    int nw = blockDim.x >> 6;
    if (wid == 0) {
        float2 v = (lane < nw) ? scratch[lane] : make_float2(0.f, 0.f);
        a = v.x; b = v.y;
        #pragma unroll
        for (int off = 8; off > 0; off >>= 1) {
            a += __shfl_down(a, off);
            b += __shfl_down(b, off);
        }
        if (lane == 0) scratch[0] = make_float2(a, b);
    }
    __syncthreads();
    float2 r = scratch[0];
    a = r.x; b = r.y;
}

// ---------------- KWT: W[h][256][NB] fp32 -> Wt[h][NB][256] bf16 (transpose for k-contiguous frags)
__global__ void kwt(const float* __restrict__ W, ubf* __restrict__ Wt, int NB) {
    int b = blockIdx.x;           // h*NB + n
    int h = b / NB, n = b % NB;
    int k = threadIdx.x;          // 0..255
    Wt[((size_t)h * NB + n) * 256 + k] = f2bf(W[((size_t)h * 256 + k) * NB + n]);
}

// ---------------- K1: per-chunk sums along S for the cumsum + emit in as bf16
__global__ void k1_chunksum(const float* __restrict__ in, float* __restrict__ chunk,
                            ubf* __restrict__ in_bf) {
    int bid = blockIdx.x;                 // b*HH*NC1 + h*NC1 + c
    int c = bid % NC1;
    int h = (bid / NC1) % HH;
    int b = bid / (NC1 * HH);
    int d = threadIdx.x;                  // 0..127
    size_t base = (size_t)(b * SS + c * CS1) * HD + h * DI + d;
    float s = 0.f;
    for (int i = 0; i < CS1; ++i) {
        float v = in[base + (size_t)i * HD];
        in_bf[base + (size_t)i * HD] = f2bf(v);
        s += v;
    }
    chunk[((b * NC1 + c) * HH + h) * DI + d] = s;
}

// ---------------- K2: serial exclusive scan over chunks (in-place)
__global__ void k2_chunkscan(float* __restrict__ chunk) {
    int bid = blockIdx.x;                 // b*HH + h
    int h = bid % HH;
    int b = bid / HH;
    int d = threadIdx.x;
    float run = 0.f;
    for (int c = 0; c < NC1; ++c) {
        int idx = ((b * NC1 + c) * HH + h) * DI + d;
        float v = chunk[idx];
        chunk[idx] = run;
        run += v;
    }
}

// ---------------- K3: in-chunk exclusive cumsum + LayerNorm over (H,DI)=1024 per token -> csln bf16
__global__ void __launch_bounds__(1024) k3_csum_ln(
        const float* __restrict__ in, const float* __restrict__ chunkpre,
        const float* __restrict__ g, const float* __restrict__ beta,
        ubf* __restrict__ out) {
    __shared__ float2 scratch[16];
    int c = blockIdx.x % NC1;
    int b = blockIdx.x / NC1;
    int t = threadIdx.x;                  // h*DI + d, 0..1023
    float run = chunkpre[(b * NC1 + c) * HD + t];
    const float* pin = in + (size_t)(b * SS + c * CS1) * HD + t;
    ubf* pout = out + (size_t)(b * SS + c * CS1) * HD + t;
    float gg = g[t], bb = beta[t];
    for (int i = 0; i < CS1; ++i) {
        float v = pin[(size_t)i * HD];
        float cs = run;
        run += v;
        float a = cs, b2 = cs * cs;
        blockReduce2(a, b2, scratch);
        float mu  = a * (1.f / 1024.f);
        float var = b2 * (1.f / 1024.f) - mu * mu;
        float r = rsqrtf(var + LNEPS);
        pout[(size_t)i * HD] = f2bf((cs - mu) * r * gg + bb);
    }
}

// ---------------- GEMM (MFMA, LDS-free): per-head C over [Ab0_h | Ab1_h](tok,256) @ Wt[h]^T, +bias.
// Each wave owns 64 tokens: FULL A-slice (64x256) in registers, loaded ONCE (A HBM traffic exact).
// Wave loops over all n-slices (64 wide) of its head; B frags double-buffered, streamed from
// L1/L2 (Wt = 1.5MB, L2-resident). No LDS, no barriers, no bank conflicts, no vmcnt(0) drain.
// MFMA operands SWAPPED (mfma(Bfrag, Afrag)): D rows = n -> reg quad runs along n -> u16x4 stores.
// C layout PERMUTED for lane-local gates: col = (n>>7)*1024 + h*128 + (n&127), row stride NB*8.
#define GLOADB(BF, KS, NSB)                                                              \
    do {                                                                                 \
        _Pragma("unroll")                                                                \
        for (int j_ = 0; j_ < 4; ++j_)                                                   \
            BF[j_] = *(const bf16x8*)(pWt + (size_t)((NSB) + j_ * 16) * 256 + (KS) * 32);\
    } while (0)

#define GMFMA(KS, BF)                                                                    \
    do {                                                                                 \
        _Pragma("unroll")                                                                \
        for (int i_ = 0; i_ < 4; ++i_)                                                   \
            _Pragma("unroll")                                                            \
            for (int j_ = 0; j_ < 4; ++j_)                                               \
                acc[i_][j_] = __builtin_amdgcn_mfma_f32_16x16x32_bf16(                   \
                    BF[j_], areg[KS][i_], acc[i_][j_], 0, 0, 0);                         \
    } while (0)

__global__ void __launch_bounds__(256, 2) gemm_h(
        const ubf* __restrict__ Ab0, const ubf* __restrict__ Ab1,
        const ubf* __restrict__ Wt, const float* __restrict__ bias,
        ubf* __restrict__ C, int NB) {
    int t = threadIdx.x;
    int lane = t & 63, w = t >> 6;
    int h = blockIdx.y;
    int tok0w = (blockIdx.x * 4 + w) * 64;
    int crs = NB * HH;                    // C row stride

    // ---- load full A-slice into registers: areg[ks][i] = rows tok0w+i*16+(lane&15), k=ks*32+(lane>>4)*8
    size_t offA = (size_t)(tok0w + (lane & 15)) * HD + h * DI + (lane >> 4) * 8;
    const ubf* a0p = Ab0 + offA;
    const ubf* a1p = Ab1 + offA;
    bf16x8 areg[8][4];
    #pragma unroll
    for (int ks = 0; ks < 4; ++ks)
        #pragma unroll
        for (int i = 0; i < 4; ++i)
            areg[ks][i] = *(const bf16x8*)(a0p + (size_t)i * 16 * HD + ks * 32);
    #pragma unroll
    for (int ks = 4; ks < 8; ++ks)
        #pragma unroll
        for (int i = 0; i < 4; ++i)
            areg[ks][i] = *(const bf16x8*)(a1p + (size_t)i * 16 * HD + (ks * 32 - 128));

    const ubf* pWt = Wt + ((size_t)h * NB + (lane & 15)) * 256 + (lane >> 4) * 8;
    int nslices = NB >> 6;

    for (int ns = 0; ns < nslices; ++ns) {
        int nsb = ns * 64;
        f32x4 acc[4][4];
        #pragma unroll
        for (int i = 0; i < 4; ++i)
            #pragma unroll
            for (int j = 0; j < 4; ++j) acc[i][j] = (f32x4){0.f, 0.f, 0.f, 0.f};

        bf16x8 b0[4], b1[4];
        GLOADB(b0, 0, nsb);
        GLOADB(b1, 1, nsb);
        #pragma unroll
        for (int ks = 0; ks < 8; ks += 2) {
            GMFMA(ks, b0);
            if (ks + 2 < 8) GLOADB(b0, ks + 2, nsb);
            GMFMA(ks + 1, b1);
            if (ks + 3 < 8) GLOADB(b1, ks + 3, nsb);
        }

        // epilogue: D rows = n (reg quad), cols = token (lane&15). u16x4 store along n.
        int nq = nsb + (lane >> 4) * 4;
        #pragma unroll
        for (int j = 0; j < 4; ++j) {
            int n = nq + j * 16;
            f32x4 bv = *(const f32x4*)(bias + h * NB + n);
            int col = (n >> 7) * 1024 + h * 128 + (n & 127);
            #pragma unroll
            for (int i = 0; i < 4; ++i) {
                u16x4 o;
                o[0] = f2bf(acc[i][j][0] + bv[0]);
                o[1] = f2bf(acc[i][j][1] + bv[1]);
                o[2] = f2bf(acc[i][j][2] + bv[2]);
                o[3] = f2bf(acc[i][j][3] + bv[3]);
                *(u16x4*)(C + (size_t)(tok0w + i * 16 + (lane & 15)) * crs + col) = o;
            }
        }
    }
}

// ---------------- K4b (wave-per-token, 16384 waves): LN over 3072 (bias pre-folded in gemm), gates.
__global__ void __launch_bounds__(256, 4) k4b_ln_gates(
        const ubf* __restrict__ h3, const float* __restrict__ g,
        const float* __restrict__ beta, ubf* __restrict__ fgl, float* __restrict__ igh) {
    int lane = threadIdx.x & 63;
    int tok  = blockIdx.x * 4 + (threadIdx.x >> 6);
    int c0 = 8 * lane;                    // col base within a part-plane (q=1 adds 512)
    const ubf* p = h3 + (size_t)tok * 3072;

    u16x8 raw[6];
    #pragma unroll
    for (int pp = 0; pp < 3; ++pp) {
        raw[pp * 2 + 0] = *(const u16x8*)(p + pp * 1024 + c0);
        raw[pp * 2 + 1] = *(const u16x8*)(p + pp * 1024 + 512 + c0);
    }
    float sum = 0.f, sq = 0.f;
    #pragma unroll
    for (int s = 0; s < 6; ++s) {
        #pragma unroll
        for (int j = 0; j < 8; ++j) {
            float a = bf2f((ubf)raw[s][j]);
            sum += a; sq = fmaf(a, a, sq);
        }
    }
    #pragma unroll
    for (int m = 32; m >= 1; m >>= 1) {
        sum += __shfl_xor(sum, m);
        sq  += __shfl_xor(sq, m);
    }
    float mu = sum * (1.f / 3072.f);
    float r  = rsqrtf(sq * (1.f / 3072.f) - mu * mu + LNEPS);

    int dd = c0 & 127;
    size_t ob = (size_t)tok * HD + c0;
    #pragma unroll
    for (int q = 0; q < 2; ++q) {
        int hq = (c0 + q * 512) >> 7;
        int gb = hq * 384 + dd;           // g_hid/beta_hid are [h][part][d]
        f32x4 gv[3][2], bv[3][2];
        #pragma unroll
        for (int pp = 0; pp < 3; ++pp) {
            gv[pp][0] = *(const f32x4*)(g + gb + pp * 128);
            gv[pp][1] = *(const f32x4*)(g + gb + pp * 128 + 4);
            bv[pp][0] = *(const f32x4*)(beta + gb + pp * 128);
            bv[pp][1] = *(const f32x4*)(beta + gb + pp * 128 + 4);
        }
        u16x8 fo;
        f32x4 io0, io1;
        #pragma unroll
        for (int j = 0; j < 8; ++j) {
            float ai = bf2f((ubf)raw[0 + q][j]);
            float af = bf2f((ubf)raw[2 + q][j]);
            float ah = bf2f((ubf)raw[4 + q][j]);
            float li = (ai - mu) * r * gv[0][j >> 2][j & 3] + bv[0][j >> 2][j & 3];
            float lf = (af - mu) * r * gv[1][j >> 2][j & 3] + bv[1][j >> 2][j & 3];
            float lh = (ah - mu) * r * gv[2][j >> 2][j & 3] + bv[2][j >> 2][j & 3];
            fo[j] = f2bf(lf);
            float v = fast_sigmoid(li) * fmaxf(lh, 0.f);
            if (j < 4) io0[j & 3] = v; else io1[j & 3] = v;
        }
        *(u16x8*)(fgl + ob + q * 512) = fo;
        *(f32x4*)(igh + ob + q * 512) = io0;
        *(f32x4*)(igh + ob + q * 512 + 4) = io1;
    }
}

// ---------------- K5a: per-chunk recurrence summary: P = prod f, L = local end value
__global__ void k5a_chunkrec(const ubf* __restrict__ fgl, const float* __restrict__ igh,
                             float* __restrict__ Pb, float* __restrict__ Lb) {
    int bid = blockIdx.x;                 // b*NC2*HH + c*HH + h
    int h = bid % HH;
    int c = (bid / HH) % NC2;
    int b = bid / (HH * NC2);
    int d = threadIdx.x;
    size_t base = (size_t)(b * SS + c * CS2) * HD + h * DOo + d;
    float P = 1.f, L = 0.f;
    for (int s = 0; s < CS2; ++s) {
        float f = 1.f / (1.f + expf(-bf2f(fgl[base + (size_t)s * HD])));
        float i = igh[base + (size_t)s * HD];
        L = f * L + i;
        P *= f;
    }
    int o = ((b * NC2 + c) * HH + h) * DOo + d;
    Pb[o] = P;
    Lb[o] = L;
}

// ---------------- K5b: serial carry across chunks
__global__ void k5b_carry(const float* __restrict__ Pb, const float* __restrict__ Lb,
                          const float* __restrict__ init_cx, float* __restrict__ cIn) {
    int bid = blockIdx.x;                 // b*HH + h
    int h = bid % HH;
    int b = bid / HH;
    int d = threadIdx.x;
    float c = init_cx[h * DOo + d];
    for (int cc = 0; cc < NC2; ++cc) {
        int o = ((b * NC2 + cc) * HH + h) * DOo + d;
        cIn[o] = c;
        c = Pb[o] * c + Lb[o];
    }
}

// ---------------- K5c: final in-chunk recurrence; cell fp32 in-place over igh (d_out) + cell bf16 copy
__global__ void k5c_cell(const ubf* __restrict__ fgl, float* __restrict__ igh_cell,
                         const float* __restrict__ cIn, ubf* __restrict__ cell_bf) {
    int bid = blockIdx.x;
    int h = bid % HH;
    int c = (bid / HH) % NC2;
    int b = bid / (HH * NC2);
    int d = threadIdx.x;
    size_t base = (size_t)(b * SS + c * CS2) * HD + h * DOo + d;
    int o = ((b * NC2 + c) * HH + h) * DOo + d;
    float cv = cIn[o];
    for (int s = 0; s < CS2; ++s) {
        float f = 1.f / (1.f + expf(-bf2f(fgl[base + (size_t)s * HD])));
        float i = igh_cell[base + (size_t)s * HD];
        cv = f * cv + i;
        igh_cell[base + (size_t)s * HD] = cv;
        cell_bf[base + (size_t)s * HD] = f2bf(cv);
    }
}

// ---------------- K6b (wave-per-token): LN over 1024 (bias pre-folded in og gemm), sigmoid*cell -> out.
__global__ void __launch_bounds__(256, 4) k6b_ln_out(
        const ubf* __restrict__ ogr, float* __restrict__ out /* cell in, final out */,
        const float* __restrict__ g, const float* __restrict__ beta) {
    int lane = threadIdx.x & 63;
    int tok  = blockIdx.x * 4 + (threadIdx.x >> 6);
    int c0 = 8 * lane;
    size_t base = (size_t)tok * HD + c0;

    u16x8 og0 = *(const u16x8*)(ogr + base);
    u16x8 og1 = *(const u16x8*)(ogr + base + 512);
    f32x4 cl[2][2];
    cl[0][0] = *(const f32x4*)(out + base);
    cl[0][1] = *(const f32x4*)(out + base + 4);
    cl[1][0] = *(const f32x4*)(out + base + 512);
    cl[1][1] = *(const f32x4*)(out + base + 512 + 4);

    float sum = 0.f, sq = 0.f;
    #pragma unroll
    for (int j = 0; j < 8; ++j) {
        float a0 = bf2f((ubf)og0[j]);
        float a1 = bf2f((ubf)og1[j]);
        sum += a0 + a1;
        sq = fmaf(a0, a0, sq);
        sq = fmaf(a1, a1, sq);
    }
    #pragma unroll
    for (int m = 32; m >= 1; m >>= 1) {
        sum += __shfl_xor(sum, m);
        sq  += __shfl_xor(sq, m);
    }
    float mu = sum * (1.f / 1024.f);
    float r  = rsqrtf(sq * (1.f / 1024.f) - mu * mu + LNEPS);

    #pragma unroll
    for (int q = 0; q < 2; ++q) {
        f32x4 gv0 = *(const f32x4*)(g + q * 512 + c0);
        f32x4 gv1 = *(const f32x4*)(g + q * 512 + c0 + 4);
        f32x4 bv0 = *(const f32x4*)(beta + q * 512 + c0);
        f32x4 bv1 = *(const f32x4*)(beta + q * 512 + c0 + 4);
        f32x4 o0, o1;
        #pragma unroll
        for (int j = 0; j < 8; ++j) {
            float a = bf2f((ubf)(q ? og1[j] : og0[j]));
            float gg = (j < 4) ? gv0[j & 3] : gv1[j & 3];
            float bb = (j < 4) ? bv0[j & 3] : bv1[j & 3];
            float lo = (a - mu) * r * gg + bb;
            float v = fast_sigmoid(lo) * cl[q][j >> 2][j & 3];
            if (j < 4) o0[j & 3] = v; else o1[j & 3] = v;
        }
        *(f32x4*)(out + base + q * 512) = o0;
        *(f32x4*)(out + base + q * 512 + 4) = o1;
    }
}

extern "C" void kernel_launch(void* const* d_in, const int* in_sizes, int n_in,
                              void* d_out, int out_size, void* d_ws, size_t ws_size,
                              hipStream_t stream) {
    const float* heads_input = (const float*)d_in[0];
    const float* W_hid   = (const float*)d_in[1];
    const float* b_hid   = (const float*)d_in[2];
    const float* g_csum  = (const float*)d_in[3];
    const float* beta_csum = (const float*)d_in[4];
    const float* g_hid   = (const float*)d_in[5];
    const float* beta_hid = (const float*)d_in[6];
    const float* W_og    = (const float*)d_in[7];
    const float* b_og    = (const float*)d_in[8];
    const float* g_og    = (const float*)d_in[9];
    const float* beta_og = (const float*)d_in[10];
    const float* init_cx = (const float*)d_in[11];
    float* out = (float*)d_out;           // fp32 output, NTOK*HD elements

    // workspace layout (~172.5 MB)
    char* ws = (char*)d_ws;
    ubf* in_bf   = (ubf*)ws;                                   // 33,554,432 B
    ubf* csln_bf = (ubf*)(ws + (size_t)33554432);              // 33,554,432 B (later fgl)
    ubf* big     = (ubf*)(ws + (size_t)67108864);              // 100,663,296 B
    ubf* h3      = big;                                        // k4a w, k4b r
    ubf* cell_bf = big;                                        // k5c w, k6a r (h3 dead)
    ubf* og_bf   = big + (size_t)NTOK * HD;                    // k6a w, k6b r
    char* tail   = ws + (size_t)167772160;
    float* chunk = (float*)tail;                               // 1,048,576 B
    float* Pb    = chunk + (size_t)BB * NC1 * HD;              //   524,288 B
    float* Lb    = Pb + (size_t)BB * NC2 * HD;                 //   524,288 B
    float* cIn   = Lb + (size_t)BB * NC2 * HD;                 //   524,288 B
    ubf* Wt_hid  = (ubf*)(cIn + (size_t)BB * NC2 * HD);        // 1,572,864 B
    ubf* Wt_og   = Wt_hid + (size_t)HH * 384 * 256;            //   524,288 B
    ubf* fgl     = csln_bf;   // alias: csln consumed by gemm(k4a) before k4b writes fgl

    kwt<<<HH * 384, 256, 0, stream>>>(W_hid, Wt_hid, 384);
    kwt<<<HH * 128, 256, 0, stream>>>(W_og, Wt_og, 128);
    k1_chunksum<<<BB * HH * NC1, 128, 0, stream>>>(heads_input, chunk, in_bf);
    k2_chunkscan<<<BB * HH, 128, 0, stream>>>(chunk);
    k3_csum_ln<<<BB * NC1, 1024, 0, stream>>>(heads_input, chunk, g_csum, beta_csum, csln_bf);
    gemm_h<<<dim3(NTOK / 256, HH), 256, 0, stream>>>(in_bf, csln_bf, Wt_hid, b_hid, h3, 384);
    k4b_ln_gates<<<NTOK / 4, 256, 0, stream>>>(h3, g_hid, beta_hid, fgl, out);
    k5a_chunkrec<<<BB * NC2 * HH, 128, 0, stream>>>(fgl, out, Pb, Lb);
    k5b_carry<<<BB * HH, 128, 0, stream>>>(Pb, Lb, init_cx, cIn);
    k5c_cell<<<BB * NC2 * HH, 128, 0, stream>>>(fgl, out, cIn, cell_bf);
    gemm_h<<<dim3(NTOK / 256, HH), 256, 0, stream>>>(in_bf, cell_bf, Wt_og, b_og, og_bf, 128);
    k6b_ln_out<<<NTOK / 4, 256, 0, stream>>>(og_bf, out, g_og, beta_og);
}